// Round 3
// baseline (1033.140 us; speedup 1.0000x reference)
//
#include <hip/hip_runtime.h>

#define FDIM 100
#define SEQ 101
#define DIM 32
#define DEPTH 6
#define HEADS 8
#define DH 16
#define FFH 128
#define FYH 1000
#define LN_EPS 1e-5f

typedef _Float16 f16;
typedef __attribute__((ext_vector_type(4))) _Float16 f16x4;
typedef __attribute__((ext_vector_type(8))) _Float16 f16x8;
typedef __attribute__((ext_vector_type(4))) float f32x4;

#define ZSTR 37   // odd-ish stride: bank = (5s+c)%32 -> LN reads conflict-free, ds_add ~2-way
#define YSTR 36   // f16, rows 8B-aligned for ds_read_b64

// d_ws layout (f16 element offsets). Fragment order: value for (lane, reg i) is
// contiguous so each lane loads one dwordx2 per fragment.
#define WQ_OFF  0        // [l][h][q3][kk2][lane64][i4]   wqkv frags (q==0 scaled by 0.25)
#define WO_OFF  73728    // [l][h][ct2][lane][i4]         wout^T frags
#define F1_OFF  98304    // [l][jt8][kk2][lane][i4]       ff_w1^T frags
#define F2_OFF  122880   // [l][ct2][jt8][lane][i4]       ff_w2^T frags
#define EW2_OFF 147456   // [f][j4 25][d32][i4]           mlp_w2 packed 4j per lane-dword2
#define EWB_OFF 467456   // [f][j4 25][8] = w1[j..j+3], b1[j..j+3]
#define WS_TOTAL 487456  // f16 elements = 974912 B

// MFMA 16x16x16 f16 lane layout:
//  A-frag: lane l holds A[l15][4*l4+i]; B-frag: B[4*l4+i][l15]; D: lane reg r = D[4*l4+r][l15]

__device__ __forceinline__ f32x4 mfma16(f16x4 a, f16x4 b, f32x4 c) {
  return __builtin_amdgcn_mfma_f32_16x16x16f16(a, b, c, 0, 0, 0);
}
__device__ __forceinline__ f16x4 pack4(f32x4 v) {
  f16x4 r;
  r[0] = (f16)v[0]; r[1] = (f16)v[1]; r[2] = (f16)v[2]; r[3] = (f16)v[3];
  return r;
}

// ---------------- prologue: weights -> f16 fragment layouts in d_ws ----------------
__global__ void prep_weights(const float* __restrict__ wqkv, const float* __restrict__ wout,
                             const float* __restrict__ ff_w1, const float* __restrict__ ff_w2,
                             const float* __restrict__ mlp_w1, const float* __restrict__ mlp_b1,
                             const float* __restrict__ mlp_w2, f16* __restrict__ ws) {
  for (int e = blockIdx.x * blockDim.x + threadIdx.x; e < WS_TOTAL; e += gridDim.x * blockDim.x) {
    float v;
    if (e < WO_OFF) {                       // WQ
      int o = e, i = o & 3, lane = (o >> 2) & 63, kk = (o >> 8) & 1, rest = o >> 9;
      int q = rest % 3, lh = rest / 3, h = lh & 7, l = lh >> 3;
      int k = kk * 16 + 4 * (lane >> 4) + i;
      v = wqkv[((size_t)l * 32 + k) * 384 + q * 128 + h * 16 + (lane & 15)];
      if (q == 0) v *= 0.25f;               // fold DH^-0.5
    } else if (e < F1_OFF) {                // WO
      int o = e - WO_OFF, i = o & 3, lane = (o >> 2) & 63, ct = (o >> 8) & 1, lh = o >> 9;
      int h = lh & 7, l = lh >> 3;
      v = wout[((size_t)l * 128 + h * 16 + 4 * (lane >> 4) + i) * 32 + ct * 16 + (lane & 15)];
    } else if (e < F2_OFF) {                // F1
      int o = e - F1_OFF, i = o & 3, lane = (o >> 2) & 63, kk = (o >> 8) & 1, lj = o >> 9;
      int jt = lj & 7, l = lj >> 3;
      v = ff_w1[((size_t)l * 32 + kk * 16 + 4 * (lane >> 4) + i) * 128 + jt * 16 + (lane & 15)];
    } else if (e < EW2_OFF) {               // F2
      int o = e - F2_OFF, i = o & 3, lane = (o >> 2) & 63, jt = (o >> 8) & 7, lc = o >> 11;
      int ct = lc & 1, l = lc >> 1;
      v = ff_w2[((size_t)l * 128 + jt * 16 + 4 * (lane >> 4) + i) * 32 + ct * 16 + (lane & 15)];
    } else if (e < EWB_OFF) {               // EW2
      int o = e - EW2_OFF, i = o & 3, d = (o >> 2) & 31, j4 = (o >> 7) % 25, f = o / 3200;
      v = mlp_w2[((size_t)f * 100 + j4 * 4 + i) * 32 + d];
    } else {                                // EWB
      int o = e - EWB_OFF, i = o & 7, j4 = (o >> 3) % 25, f = o / 200;
      int j = j4 * 4 + (i & 3);
      v = (i < 4) ? mlp_w1[f * 100 + j] : mlp_b1[f * 100 + j];
    }
    ws[e] = (f16)v;
  }
}

// ---------------- fused transformer, one row per block ----------------
__global__ __launch_bounds__(256, 4) void saint_mfma(
    const float* __restrict__ x,
    const float* __restrict__ mlp_b2,
    const float* __restrict__ mask_emb,
    const float* __restrict__ cat_emb,
    const float* __restrict__ ln1_g, const float* __restrict__ ln1_b,
    const float* __restrict__ bout,
    const float* __restrict__ ln2_g, const float* __restrict__ ln2_b,
    const float* __restrict__ ff_b1, const float* __restrict__ ff_b2,
    const float* __restrict__ fy_w1, const float* __restrict__ fy_b1,
    const float* __restrict__ fy_w2, const float* __restrict__ fy_b2,
    const f16* __restrict__ ws,
    float* __restrict__ out)
{
  __shared__ float Z[SEQ][ZSTR];   // fp32 residual stream
  __shared__ f16  Yh[112][YSTR];   // f16 LN output (MFMA operand); rows 101..111 stay zero
  __shared__ float red[4];

  const int b = blockIdx.x;
  const int tid = threadIdx.x;
  const int lane = tid & 63;
  const int wid = tid >> 6;
  const int l15 = lane & 15;
  const int l4 = lane >> 4;

  const f32x4 zero4 = {0.f, 0.f, 0.f, 0.f};

  // zero Yh pad rows once (no other writer touches them)
  for (int i = tid; i < 11 * YSTR; i += 256) Yh[101 + i / YSTR][i % YSTR] = (f16)0.f;

  // ---------------- feature-embed MLP (f16 packed weights) ----------------
  {
    const int d = tid & 31, grp = tid >> 5;
    if (tid < DIM) {
      int ci = (int)x[(size_t)b * SEQ];
      Z[0][tid] = cat_emb[ci * DIM + tid];
    }
    const f16* ew2 = ws + EW2_OFF;
    const f16* ewb = ws + EWB_OFF;
    for (int f = grp; f < FDIM; f += 8) {
      float xv = x[(size_t)b * SEQ + 1 + f];
      float acc;
      if (xv != xv) {
        acc = mask_emb[(2 * f) * DIM + d];
      } else {
        float a0 = 0.f, a1 = 0.f;
        const f16* wb = ewb + f * 200;
        const f16* w2 = ew2 + f * 3200 + d * 4;
        #pragma unroll 5
        for (int j4 = 0; j4 < 25; ++j4) {
          f16x8 bw = *(const f16x8*)(wb + j4 * 8);       // w1[0..3], b1[0..3] (broadcast)
          f16x4 wv = *(const f16x4*)(w2 + j4 * 128);     // w2 for 4 j at this d (coalesced)
          #pragma unroll
          for (int i = 0; i < 4; ++i) {
            float h = fmaxf(fmaf(xv, (float)bw[i], (float)bw[4 + i]), 0.f);
            if (i & 1) a1 = fmaf(h, (float)wv[i], a1);
            else       a0 = fmaf(h, (float)wv[i], a0);
          }
        }
        acc = a0 + a1 + mlp_b2[f * DIM + d];
      }
      Z[1 + f][d] = acc;
    }
  }
  __syncthreads();

  for (int l = 0; l < DEPTH; ++l) {
    // ---- LN1: Yh = f16(ln(Z)); Z = ln(Z) + bout (in-place fp32 residual base) ----
    {
      const int d = tid & 31, sg = tid >> 5;
      const float gv = ln1_g[l * DIM + d], bv = ln1_b[l * DIM + d], ov = bout[l * DIM + d];
      for (int s = sg; s < SEQ; s += 8) {
        float v = Z[s][d];
        float m = v;
        #pragma unroll
        for (int off = 16; off; off >>= 1) m += __shfl_xor(m, off, 32);
        m *= 0.03125f;
        float cv = v - m;
        float vr = cv * cv;
        #pragma unroll
        for (int off = 16; off; off >>= 1) vr += __shfl_xor(vr, off, 32);
        float ln = cv * rsqrtf(vr * 0.03125f + LN_EPS) * gv + bv;
        Yh[s][d] = (f16)ln;
        Z[s][d] = ln + ov;
      }
    }
    __syncthreads();

    // ---- attention: 2 heads per wave, fully in registers; proj -> ds_add into Z ----
    #pragma unroll 1
    for (int hh = 0; hh < 2; ++hh) {
      const int h = wid * 2 + hh;
      const f16* pq = ws + WQ_OFF + (size_t)(l * 8 + h) * 1536 + lane * 4;
      const f16x4 aQ0 = *(const f16x4*)pq;
      const f16x4 aQ1 = *(const f16x4*)(pq + 256);
      const f16x4 aK0 = *(const f16x4*)(pq + 512);
      const f16x4 aK1 = *(const f16x4*)(pq + 768);
      const f16x4 bV0 = *(const f16x4*)(pq + 1024);
      const f16x4 bV1 = *(const f16x4*)(pq + 1280);
      const f16* pw = ws + WO_OFF + (size_t)(l * 8 + h) * 512 + lane * 4;
      const f16x4 aW0 = *(const f16x4*)pw;
      const f16x4 aW1 = *(const f16x4*)(pw + 256);

      // QKV for all 7 s-tiles; D-frags ARE the next stage's operand frags
      f16x4 fQ[7], fK[7], fV[7];
      #pragma unroll
      for (int t = 0; t < 7; ++t) {
        const int s = t * 16 + l15;
        f16x4 y0 = *(const f16x4*)&Yh[s][4 * l4];
        f16x4 y1 = *(const f16x4*)&Yh[s][16 + 4 * l4];
        f32x4 dQ = mfma16(aQ0, y0, zero4); dQ = mfma16(aQ1, y1, dQ);  // Q^T frag
        f32x4 dK = mfma16(aK0, y0, zero4); dK = mfma16(aK1, y1, dK);  // K^T frag
        f32x4 dV = mfma16(y0, bV0, zero4); dV = mfma16(y1, bV1, dV);  // V frag
        fQ[t] = pack4(dQ); fK[t] = pack4(dK); fV[t] = pack4(dV);
      }

      #pragma unroll
      for (int ns = 0; ns < 7; ++ns) {
        f32x4 L[7];
        #pragma unroll
        for (int jt = 0; jt < 7; ++jt) L[jt] = mfma16(fK[jt], fQ[ns], zero4);
        // softmax without max-subtraction (|logits| <~ 0.7 analytically)
        f32x4 sv = zero4;
        f16x4 bP[7];
        #pragma unroll
        for (int jt = 0; jt < 7; ++jt) {
          f32x4 e;
          #pragma unroll
          for (int r = 0; r < 4; ++r) {
            if (jt == 6) e[r] = (4 * l4 + r > 4) ? 0.f : __expf(L[jt][r]);
            else         e[r] = __expf(L[jt][r]);
          }
          sv += e;
          bP[jt] = pack4(e);   // unnormalized P^T frag
        }
        float sum = sv[0] + sv[1] + sv[2] + sv[3];
        sum += __shfl_xor(sum, 16);
        sum += __shfl_xor(sum, 32);
        const float inv = 1.f / sum;
        f32x4 Oa = zero4, Obb = zero4;
        #pragma unroll
        for (int jt = 0; jt < 7; jt += 2) Oa = mfma16(fV[jt], bP[jt], Oa);
        #pragma unroll
        for (int jt = 1; jt < 7; jt += 2) Obb = mfma16(fV[jt], bP[jt], Obb);
        f16x4 bO;
        #pragma unroll
        for (int r = 0; r < 4; ++r) bO[r] = (f16)((Oa[r] + Obb[r]) * inv);
        f32x4 z0 = mfma16(aW0, bO, zero4);   // proj c-tile 0, D[c][s]
        f32x4 z1 = mfma16(aW1, bO, zero4);   // proj c-tile 1
        const int s = ns * 16 + l15;
        if (s < SEQ) {
          #pragma unroll
          for (int r = 0; r < 4; ++r) atomicAdd(&Z[s][4 * l4 + r], z0[r]);
          #pragma unroll
          for (int r = 0; r < 4; ++r) atomicAdd(&Z[s][16 + 4 * l4 + r], z1[r]);
        }
      }
    }
    __syncthreads();

    // ---- hoist FF weight frags (hide load latency under LN2) ----
    f16x4 a1[8][2], a2[2][8];
    {
      const f16* p1 = ws + F1_OFF + (size_t)l * 4096 + lane * 4;
      const f16* p2 = ws + F2_OFF + (size_t)l * 4096 + lane * 4;
      #pragma unroll
      for (int jt = 0; jt < 8; ++jt) {
        a1[jt][0] = *(const f16x4*)(p1 + (jt * 2 + 0) * 256);
        a1[jt][1] = *(const f16x4*)(p1 + (jt * 2 + 1) * 256);
        a2[0][jt] = *(const f16x4*)(p2 + jt * 256);
        a2[1][jt] = *(const f16x4*)(p2 + (8 + jt) * 256);
      }
    }

    // ---- LN2: Yh = f16(ln(Z)); Z = ln(Z) + ff_b2 ----
    {
      const int d = tid & 31, sg = tid >> 5;
      const float gv = ln2_g[l * DIM + d], bv = ln2_b[l * DIM + d], ov = ff_b2[l * DIM + d];
      for (int s = sg; s < SEQ; s += 8) {
        float v = Z[s][d];
        float m = v;
        #pragma unroll
        for (int off = 16; off; off >>= 1) m += __shfl_xor(m, off, 32);
        m *= 0.03125f;
        float cv = v - m;
        float vr = cv * cv;
        #pragma unroll
        for (int off = 16; off; off >>= 1) vr += __shfl_xor(vr, off, 32);
        float ln = cv * rsqrtf(vr * 0.03125f + LN_EPS) * gv + bv;
        Yh[s][d] = (f16)ln;
        Z[s][d] = ln + ov;
      }
    }
    __syncthreads();

    // ---- FF: per wave s-tiles {wid, wid+4}; FF1 D-frag feeds FF2 B-frag directly ----
    #pragma unroll
    for (int t = 0; t < 2; ++t) {
      const int ns = wid + 4 * t;
      if (ns < 7) {
        const int s = ns * 16 + l15;
        f16x4 y0 = *(const f16x4*)&Yh[s][4 * l4];
        f16x4 y1 = *(const f16x4*)&Yh[s][16 + 4 * l4];
        f16x4 bH[8];
        #pragma unroll
        for (int jt = 0; jt < 8; ++jt) {
          f32x4 d = mfma16(a1[jt][0], y0, zero4);
          d = mfma16(a1[jt][1], y1, d);
          const f32x4 bb = *(const f32x4*)(ff_b1 + l * FFH + jt * 16 + 4 * l4);
          f16x4 hv;
          #pragma unroll
          for (int r = 0; r < 4; ++r) {
            float v = d[r] + bb[r];
            hv[r] = (f16)(0.5f * v * (1.f + erff(v * 0.70710678118654752440f)));
          }
          bH[jt] = hv;
        }
        f32x4 d0a = zero4, d0b = zero4, d1a = zero4, d1b = zero4;
        #pragma unroll
        for (int jt = 0; jt < 8; jt += 2) {
          d0a = mfma16(a2[0][jt], bH[jt], d0a);
          d1a = mfma16(a2[1][jt], bH[jt], d1a);
        }
        #pragma unroll
        for (int jt = 1; jt < 8; jt += 2) {
          d0b = mfma16(a2[0][jt], bH[jt], d0b);
          d1b = mfma16(a2[1][jt], bH[jt], d1b);
        }
        if (s < SEQ) {
          #pragma unroll
          for (int r = 0; r < 4; ++r) Z[s][4 * l4 + r] += d0a[r] + d0b[r];
          #pragma unroll
          for (int r = 0; r < 4; ++r) Z[s][16 + 4 * l4 + r] += d1a[r] + d1b[r];
        }
      }
    }
    __syncthreads();
  }

  // ---------------- final head ----------------
  {
    float part = 0.f;
    for (int j = tid; j < FYH; j += 256) {
      float acc = fy_b1[j];
      #pragma unroll
      for (int c = 0; c < DIM; ++c) acc = fmaf(Z[0][c], fy_w1[c * FYH + j], acc);
      part += fmaxf(acc, 0.f) * fy_w2[j];
    }
    #pragma unroll
    for (int off = 32; off; off >>= 1) part += __shfl_xor(part, off, 64);
    if (lane == 0) red[wid] = part;
    __syncthreads();
    if (tid == 0) out[b] = red[0] + red[1] + red[2] + red[3] + fy_b2[0];
  }
}

extern "C" void kernel_launch(void* const* d_in, const int* in_sizes, int n_in,
                              void* d_out, int out_size, void* d_ws, size_t ws_size,
                              hipStream_t stream) {
  (void)in_sizes; (void)n_in; (void)out_size; (void)ws_size;
  f16* ws = (f16*)d_ws;
  prep_weights<<<dim3(512), dim3(256), 0, stream>>>(
      (const float*)d_in[9],  (const float*)d_in[10],
      (const float*)d_in[14], (const float*)d_in[16],
      (const float*)d_in[1],  (const float*)d_in[2],  (const float*)d_in[3], ws);
  saint_mfma<<<dim3(1024), dim3(256), 0, stream>>>(
      (const float*)d_in[0],                          // x
      (const float*)d_in[4],                          // mlp_b2
      (const float*)d_in[5],  (const float*)d_in[6],  // mask_emb, cat_emb
      (const float*)d_in[7],  (const float*)d_in[8],  // ln1_g, ln1_b
      (const float*)d_in[11],                         // bout
      (const float*)d_in[12], (const float*)d_in[13], // ln2_g, ln2_b
      (const float*)d_in[15], (const float*)d_in[17], // ff_b1, ff_b2
      (const float*)d_in[18], (const float*)d_in[19], // fy_w1, fy_b1
      (const float*)d_in[20], (const float*)d_in[21], // fy_w2, fy_b2
      ws, (float*)d_out);
}